// Round 5
// baseline (98.644 us; speedup 1.0000x reference)
//
#include <hip/hip_runtime.h>
#include <hip/hip_bf16.h>

// Problem constants
#define BB 8
#define CC 64
#define OO 64
#define HH 128
#define WWI 128
#define HWSZ (HH * WWI)     // 16384
#define KK 9                // 3x3 taps
#define II (KK * CC)        // 576

typedef __attribute__((ext_vector_type(8))) short bf16x8;
typedef __attribute__((ext_vector_type(4))) float f32x4;
typedef __attribute__((ext_vector_type(4))) unsigned int uint4v;

__device__ __forceinline__ int iclamp(int v, int lo, int hi) {
    return v < lo ? lo : (v > hi ? hi : v);
}
__device__ __forceinline__ unsigned short f2bf(float f) {  // RNE
    unsigned u = __float_as_uint(f);
    return (unsigned short)((u + 0x7fffu + ((u >> 16) & 1u)) >> 16);
}
// bf16 pair unpack: low element = u<<16, high element = u & 0xffff0000
__device__ __forceinline__ float bfl(unsigned u) { return __uint_as_float(u << 16); }
__device__ __forceinline__ float bfh(unsigned u) { return __uint_as_float(u & 0xffff0000u); }

// ---------- prep 1: x [B][C][H][W] f32 -> xt [B][H][W][C] bf16 (LDS transpose)
// 1-D grid, XCD-swizzled: b = blk&7 so image b is written from XCD b.
__global__ __launch_bounds__(256) void prep_xt(const float* __restrict__ x,
                                               unsigned short* __restrict__ xt) {
    __shared__ float tile[64][65];
    const int blk = blockIdx.x;
    const int b = blk & 7;
    const int p0 = (blk >> 3) * 64;
    const int t = threadIdx.x;
    const int a = t >> 6;   // 0..3
    const int q = t & 63;   // 0..63
    const float* xb = x + (size_t)b * CC * HWSZ + p0;
#pragma unroll
    for (int r = 0; r < 16; ++r) {
        int c = r * 4 + a;
        tile[c][q] = xb[(size_t)c * HWSZ + q];   // coalesced read
    }
    __syncthreads();
    unsigned short* xo = xt + ((size_t)b * HWSZ + p0) * CC;
#pragma unroll
    for (int r = 0; r < 16; ++r) {
        int pl = r * 4 + a;
        xo[(size_t)pl * CC + q] = f2bf(tile[q][pl]);  // coalesced 2B x 64 write
    }
}

// ---------- prep 2: W -> fragment-ordered bf16 layout
// waf[slab][lane][j], slab = (k*2+kc)*4 + m, value =
//   W.flat[o = m*16+(lane&15)][i = k*64 + kc*32 + (lane>>4)*8 + j]
__global__ void prep_waf(const float* __restrict__ w, unsigned short* __restrict__ waf) {
    int tid = blockIdx.x * 256 + threadIdx.x;
    if (tid < 72 * 512) {
        int slab = tid >> 9;           // 0..71
        int r = tid & 511;
        int l = r >> 3, j = r & 7;
        int m = slab & 3;
        int kc = (slab >> 2) & 1;
        int k = slab >> 3;
        int o = m * 16 + (l & 15);
        int i = k * 64 + kc * 32 + (l >> 4) * 8 + j;
        waf[tid] = f2bf(w[(size_t)o * II + i]);
    }
}

// ---------- main: wave-independent, no LDS, register double-buffer with
// asm-pinned wide loads (prevents the compiler from shredding/sinking them).
__global__ __launch_bounds__(256, 3) void deform_mfma4(
        const unsigned short* __restrict__ xt,   // [B][H][W][C] bf16
        const float* __restrict__ off,           // [B][2K][H][W]
        const unsigned short* __restrict__ waf,  // frag-ordered W, bf16
        const float* __restrict__ bias,          // [O]
        float* __restrict__ out) {               // [B][O][H][W]
    const int blk = blockIdx.x;
    const int b = blk & 7;                    // XCD-ownership: image b on XCD b
    const int t = threadIdx.x;
    const int wave = t >> 6;
    const int lane = t & 63;
    const int px = lane & 15;
    const int hi = lane >> 4;                 // 0..3
    const int p0 = (blk >> 3) * 64 + wave * 16;
    const int p = p0 + px;
    const int wo = p & (WWI - 1);
    const int ho = p >> 7;

    const float* offp = off + (size_t)b * 2 * KK * HWSZ + p;
    const unsigned short* xtb = xt + (size_t)b * HWSZ * CC;
    const int c0 = hi * 8;                    // channel base, kc=0 chunk
    const int c1 = 32 + hi * 8;               // channel base, kc=1 chunk

    // preload all tap offsets; loop fully unrolls -> named registers, no scratch
    float gxs[KK], gys[KK];
#pragma unroll
    for (int k = 0; k < KK; ++k) {
        gxs[k] = offp[(size_t)(2 * k + 0) * HWSZ] + (float)wo;  // padded coords
        gys[k] = offp[(size_t)(2 * k + 1) * HWSZ] + (float)ho;
    }

    f32x4 acc[4];
#pragma unroll
    for (int m = 0; m < 4; ++m) acc[m] = (f32x4)(0.0f);

    // corner-vector double buffer + folded bilinear weights
    uint4v cb[2][8];
    float  cw[2][4];

    // ISSUE(k,s): compute addresses + issue the 8 wide corner loads (no pin).
#define ISSUE(k, s) do {                                                        \
        const float gx = gxs[(k)], gy = gys[(k)];                               \
        const float fxf = floorf(gx), fyf = floorf(gy);                         \
        const float fx = gx - fxf, fy = gy - fyf;                               \
        const int ux0 = (int)fxf - 1, ux1 = (int)fxf;                           \
        const int uy0 = (int)fyf - 1, uy1 = (int)fyf;                           \
        const float vx0 = ((unsigned)ux0 < (unsigned)WWI) ? 1.0f : 0.0f;        \
        const float vx1 = ((unsigned)ux1 < (unsigned)WWI) ? 1.0f : 0.0f;        \
        const float vy0 = ((unsigned)uy0 < (unsigned)HH) ? 1.0f : 0.0f;         \
        const float vy1 = ((unsigned)uy1 < (unsigned)HH) ? 1.0f : 0.0f;         \
        cw[(s)][0] = (1.0f - fy) * (1.0f - fx) * vy0 * vx0;                     \
        cw[(s)][1] = (1.0f - fy) * fx          * vy0 * vx1;                     \
        cw[(s)][2] = fy          * (1.0f - fx) * vy1 * vx0;                     \
        cw[(s)][3] = fy          * fx          * vy1 * vx1;                     \
        const int cx0 = iclamp(ux0, 0, WWI - 1), cx1 = iclamp(ux1, 0, WWI - 1); \
        const int cy0 = iclamp(uy0, 0, HH - 1),  cy1 = iclamp(uy1, 0, HH - 1);  \
        const unsigned short* r00 = xtb + (size_t)(cy0 * WWI + cx0) * CC;       \
        const unsigned short* r01 = xtb + (size_t)(cy0 * WWI + cx1) * CC;       \
        const unsigned short* r10 = xtb + (size_t)(cy1 * WWI + cx0) * CC;       \
        const unsigned short* r11 = xtb + (size_t)(cy1 * WWI + cx1) * CC;       \
        cb[(s)][0] = *(const uint4v*)(r00 + c0);                                \
        cb[(s)][1] = *(const uint4v*)(r00 + c1);                                \
        cb[(s)][2] = *(const uint4v*)(r01 + c0);                                \
        cb[(s)][3] = *(const uint4v*)(r01 + c1);                                \
        cb[(s)][4] = *(const uint4v*)(r10 + c0);                                \
        cb[(s)][5] = *(const uint4v*)(r10 + c1);                                \
        cb[(s)][6] = *(const uint4v*)(r11 + c0);                                \
        cb[(s)][7] = *(const uint4v*)(r11 + c1);                                \
    } while (0)

    // PROCESS(k,s): pin the 8 vectors (forces wide loads, completed HERE),
    // then waf frag loads + interpolation + 8 MFMAs.
#define PROCESS(k, s) do {                                                      \
        asm volatile("" : "+v"(cb[(s)][0]), "+v"(cb[(s)][1]),                   \
                          "+v"(cb[(s)][2]), "+v"(cb[(s)][3]),                   \
                          "+v"(cb[(s)][4]), "+v"(cb[(s)][5]),                   \
                          "+v"(cb[(s)][6]), "+v"(cb[(s)][7]));                  \
        const float w00 = cw[(s)][0], w01 = cw[(s)][1];                         \
        const float w10 = cw[(s)][2], w11 = cw[(s)][3];                         \
        const unsigned short* wk = waf + (size_t)(k) * 8 * 512 + lane * 8;      \
        bf16x8 af[8];                                                           \
        _Pragma("unroll")                                                       \
        for (int q = 0; q < 8; ++q) af[q] = *(const bf16x8*)(wk + (size_t)q * 512); \
        bf16x8 bf0, bf1;                                                        \
        __hip_bfloat162* rp0 = (__hip_bfloat162*)&bf0;                          \
        __hip_bfloat162* rp1 = (__hip_bfloat162*)&bf1;                          \
        _Pragma("unroll")                                                       \
        for (int i = 0; i < 4; ++i) {                                           \
            float vlo = w00 * bfl(cb[(s)][0][i]) + w01 * bfl(cb[(s)][2][i])     \
                      + w10 * bfl(cb[(s)][4][i]) + w11 * bfl(cb[(s)][6][i]);    \
            float vhi = w00 * bfh(cb[(s)][0][i]) + w01 * bfh(cb[(s)][2][i])     \
                      + w10 * bfh(cb[(s)][4][i]) + w11 * bfh(cb[(s)][6][i]);    \
            rp0[i] = __hip_bfloat162{__float2bfloat16(vlo), __float2bfloat16(vhi)}; \
            float ulo = w00 * bfl(cb[(s)][1][i]) + w01 * bfl(cb[(s)][3][i])     \
                      + w10 * bfl(cb[(s)][5][i]) + w11 * bfl(cb[(s)][7][i]);    \
            float uhi = w00 * bfh(cb[(s)][1][i]) + w01 * bfh(cb[(s)][3][i])     \
                      + w10 * bfh(cb[(s)][5][i]) + w11 * bfh(cb[(s)][7][i]);    \
            rp1[i] = __hip_bfloat162{__float2bfloat16(ulo), __float2bfloat16(uhi)}; \
        }                                                                       \
        _Pragma("unroll")                                                       \
        for (int m = 0; m < 4; ++m)                                             \
            acc[m] = __builtin_amdgcn_mfma_f32_16x16x32_bf16(af[m], bf0, acc[m], 0, 0, 0); \
        _Pragma("unroll")                                                       \
        for (int m = 0; m < 4; ++m)                                             \
            acc[m] = __builtin_amdgcn_mfma_f32_16x16x32_bf16(af[4 + m], bf1, acc[m], 0, 0, 0); \
    } while (0)

    // Schedule: I0 I1 P0 I2 P1 I3 P2 ... I8 P7 P8
    // During PROCESS(k), tap k+1's loads are outstanding (pinned at P(k+1)).
    ISSUE(0, 0);
    ISSUE(1, 1);
    PROCESS(0, 0);
    ISSUE(2, 0);
    PROCESS(1, 1);
    ISSUE(3, 1);
    PROCESS(2, 0);
    ISSUE(4, 0);
    PROCESS(3, 1);
    ISSUE(5, 1);
    PROCESS(4, 0);
    ISSUE(6, 0);
    PROCESS(5, 1);
    ISSUE(7, 1);
    PROCESS(6, 0);
    ISSUE(8, 0);
    PROCESS(7, 1);
    PROCESS(8, 0);

#undef ISSUE
#undef PROCESS

    // epilogue: D layout col = lane&15 (px), row = hi*4 + j within each m-tile
    float* outb = out + (size_t)b * OO * HWSZ + p0 + px;
#pragma unroll
    for (int m = 0; m < 4; ++m) {
        const int ob = m * 16 + hi * 4;
        const float4 bs = *(const float4*)(bias + ob);
#pragma unroll
        for (int j = 0; j < 4; ++j) {
            outb[(size_t)(ob + j) * HWSZ] = acc[m][j] + ((const float*)&bs)[j];
        }
    }
}

// ---------- fallback (round-1 fp32 path, used only if ws too small) ----------
__global__ __launch_bounds__(256) void deform_conv_fallback(
        const float* __restrict__ x, const float* __restrict__ off,
        const float* __restrict__ wmat, const float* __restrict__ bias,
        float* __restrict__ out) {
    const int b = blockIdx.y;
    const int p = blockIdx.x * 256 + threadIdx.x;
    const int wo = p & (WWI - 1);
    const int ho = p >> 7;
    const float* xb = x + (size_t)b * CC * HWSZ;
    const float* offb = off + (size_t)b * 2 * KK * HWSZ + p;
    float acc[OO];
#pragma unroll
    for (int o = 0; o < OO; ++o) acc[o] = 0.0f;
#pragma unroll 1
    for (int k = 0; k < KK; ++k) {
        const float gx = offb[(size_t)(2 * k + 0) * HWSZ] + (float)wo;
        const float gy = offb[(size_t)(2 * k + 1) * HWSZ] + (float)ho;
        const float fxf = floorf(gx), fyf = floorf(gy);
        const float fx = gx - fxf, fy = gy - fyf;
        const int ux0 = (int)fxf - 1, ux1 = (int)fxf;
        const int uy0 = (int)fyf - 1, uy1 = (int)fyf;
        const float vx0 = ((unsigned)ux0 < (unsigned)WWI) ? 1.0f : 0.0f;
        const float vx1 = ((unsigned)ux1 < (unsigned)WWI) ? 1.0f : 0.0f;
        const float vy0 = ((unsigned)uy0 < (unsigned)HH) ? 1.0f : 0.0f;
        const float vy1 = ((unsigned)uy1 < (unsigned)HH) ? 1.0f : 0.0f;
        const float w00 = (1.0f - fy) * (1.0f - fx) * vy0 * vx0;
        const float w01 = (1.0f - fy) * fx * vy0 * vx1;
        const float w10 = fy * (1.0f - fx) * vy1 * vx0;
        const float w11 = fy * fx * vy1 * vx1;
        const int cx0 = iclamp(ux0, 0, WWI - 1), cx1 = iclamp(ux1, 0, WWI - 1);
        const int cy0 = iclamp(uy0, 0, HH - 1), cy1 = iclamp(uy1, 0, HH - 1);
        const int i00 = cy0 * WWI + cx0, i01 = cy0 * WWI + cx1;
        const int i10 = cy1 * WWI + cx0, i11 = cy1 * WWI + cx1;
#pragma unroll 4
        for (int c = 0; c < CC; ++c) {
            const float* xc = xb + (size_t)c * HWSZ;
            const float v = w00 * xc[i00] + w01 * xc[i01] + w10 * xc[i10] + w11 * xc[i11];
            const float* wrow = wmat + (size_t)(k * CC + c);
#pragma unroll
            for (int o = 0; o < OO; ++o) acc[o] = fmaf(wrow[(size_t)o * II], v, acc[o]);
        }
    }
    float* outb = out + (size_t)b * OO * HWSZ + p;
#pragma unroll
    for (int o = 0; o < OO; ++o) outb[(size_t)o * HWSZ] = acc[o] + bias[o];
}

extern "C" void kernel_launch(void* const* d_in, const int* in_sizes, int n_in,
                              void* d_out, int out_size, void* d_ws, size_t ws_size,
                              hipStream_t stream) {
    const float* x    = (const float*)d_in[0];
    const float* off  = (const float*)d_in[1];
    const float* w    = (const float*)d_in[2];
    const float* bias = (const float*)d_in[3];
    float* out = (float*)d_out;

    const size_t xt_bytes  = (size_t)BB * HWSZ * CC * sizeof(unsigned short); // 16.78 MB
    const size_t waf_bytes = (size_t)72 * 512 * sizeof(unsigned short);       // 73728 B

    if (ws_size >= xt_bytes + waf_bytes) {
        unsigned short* xt  = (unsigned short*)d_ws;
        unsigned short* wfp = (unsigned short*)((char*)d_ws + xt_bytes);
        prep_xt<<<dim3((HWSZ / 64) * BB), 256, 0, stream>>>(x, xt);
        prep_waf<<<(72 * 512 + 255) / 256, 256, 0, stream>>>(w, wfp);
        deform_mfma4<<<dim3((HWSZ / 64) * BB), 256, 0, stream>>>(xt, off, wfp, bias, out);
    } else {
        deform_conv_fallback<<<dim3(HWSZ / 256, BB), 256, 0, stream>>>(x, off, w, bias, out);
    }
}

// Round 6
// 98.480 us; speedup vs baseline: 1.0017x; 1.0017x over previous
//
#include <hip/hip_runtime.h>
#include <hip/hip_bf16.h>

// Problem constants
#define BB 8
#define CC 64
#define OO 64
#define HH 128
#define WWI 128
#define HWSZ (HH * WWI)     // 16384
#define KK 9                // 3x3 taps
#define II (KK * CC)        // 576

typedef __attribute__((ext_vector_type(8))) short bf16x8;
typedef __attribute__((ext_vector_type(4))) float f32x4;
typedef __attribute__((ext_vector_type(4))) unsigned int uint4v;

__device__ __forceinline__ int iclamp(int v, int lo, int hi) {
    return v < lo ? lo : (v > hi ? hi : v);
}
__device__ __forceinline__ unsigned short f2bf(float f) {  // RNE
    unsigned u = __float_as_uint(f);
    return (unsigned short)((u + 0x7fffu + ((u >> 16) & 1u)) >> 16);
}
// bf16 pair unpack: low element = u<<16, high element = u & 0xffff0000
__device__ __forceinline__ float bfl(unsigned u) { return __uint_as_float(u << 16); }
__device__ __forceinline__ float bfh(unsigned u) { return __uint_as_float(u & 0xffff0000u); }

// ---------- prep 1: x [B][C][H][W] f32 -> xt [B][H][W][C] bf16 (LDS transpose)
// 1-D grid, XCD-swizzled: b = blk&7 so image b is written from XCD b.
__global__ __launch_bounds__(256) void prep_xt(const float* __restrict__ x,
                                               unsigned short* __restrict__ xt) {
    __shared__ float tile[64][65];
    const int blk = blockIdx.x;
    const int b = blk & 7;
    const int p0 = (blk >> 3) * 64;
    const int t = threadIdx.x;
    const int a = t >> 6;   // 0..3
    const int q = t & 63;   // 0..63
    const float* xb = x + (size_t)b * CC * HWSZ + p0;
#pragma unroll
    for (int r = 0; r < 16; ++r) {
        int c = r * 4 + a;
        tile[c][q] = xb[(size_t)c * HWSZ + q];   // coalesced read
    }
    __syncthreads();
    unsigned short* xo = xt + ((size_t)b * HWSZ + p0) * CC;
#pragma unroll
    for (int r = 0; r < 16; ++r) {
        int pl = r * 4 + a;
        xo[(size_t)pl * CC + q] = f2bf(tile[q][pl]);  // coalesced 2B x 64 write
    }
}

// ---------- prep 2: W -> fragment-ordered bf16 layout
// waf[slab][lane][j], slab = (k*2+kc)*4 + m, value =
//   W.flat[o = m*16+(lane&15)][i = k*64 + kc*32 + (lane>>4)*8 + j]
__global__ void prep_waf(const float* __restrict__ w, unsigned short* __restrict__ waf) {
    int tid = blockIdx.x * 256 + threadIdx.x;
    if (tid < 72 * 512) {
        int slab = tid >> 9;           // 0..71
        int r = tid & 511;
        int l = r >> 3, j = r & 7;
        int m = slab & 3;
        int kc = (slab >> 2) & 1;
        int k = slab >> 3;
        int o = m * 16 + (l & 15);
        int i = k * 64 + kc * 32 + (l >> 4) * 8 + j;
        waf[tid] = f2bf(w[(size_t)o * II + i]);
    }
}

// ---------- main: wave-independent, no LDS, register double-buffer with
// asm-pinned wide loads (prevents the compiler from shredding/sinking them).
__global__ __launch_bounds__(256, 3) void deform_mfma4(
        const unsigned short* __restrict__ xt,   // [B][H][W][C] bf16
        const float* __restrict__ off,           // [B][2K][H][W]
        const unsigned short* __restrict__ waf,  // frag-ordered W, bf16
        const float* __restrict__ bias,          // [O]
        float* __restrict__ out) {               // [B][O][H][W]
    const int blk = blockIdx.x;
    const int b = blk & 7;                    // XCD-ownership: image b on XCD b
    const int t = threadIdx.x;
    const int wave = t >> 6;
    const int lane = t & 63;
    const int px = lane & 15;
    const int hi = lane >> 4;                 // 0..3
    const int p0 = (blk >> 3) * 64 + wave * 16;
    const int p = p0 + px;
    const int wo = p & (WWI - 1);
    const int ho = p >> 7;

    const float* offp = off + (size_t)b * 2 * KK * HWSZ + p;
    const unsigned short* xtb = xt + (size_t)b * HWSZ * CC;
    const int c0 = hi * 8;                    // channel base, kc=0 chunk
    const int c1 = 32 + hi * 8;               // channel base, kc=1 chunk

    // preload all tap offsets; loop fully unrolls -> named registers, no scratch
    float gxs[KK], gys[KK];
#pragma unroll
    for (int k = 0; k < KK; ++k) {
        gxs[k] = offp[(size_t)(2 * k + 0) * HWSZ] + (float)wo;  // padded coords
        gys[k] = offp[(size_t)(2 * k + 1) * HWSZ] + (float)ho;
    }

    f32x4 acc[4];
#pragma unroll
    for (int m = 0; m < 4; ++m) acc[m] = (f32x4)(0.0f);

    // corner-vector double buffer + folded bilinear weights
    uint4v cb[2][8];
    float  cw[2][4];

    // ISSUE(k,s): compute addresses + issue the 8 wide corner loads (no pin).
#define ISSUE(k, s) do {                                                        \
        const float gx = gxs[(k)], gy = gys[(k)];                               \
        const float fxf = floorf(gx), fyf = floorf(gy);                         \
        const float fx = gx - fxf, fy = gy - fyf;                               \
        const int ux0 = (int)fxf - 1, ux1 = (int)fxf;                           \
        const int uy0 = (int)fyf - 1, uy1 = (int)fyf;                           \
        const float vx0 = ((unsigned)ux0 < (unsigned)WWI) ? 1.0f : 0.0f;        \
        const float vx1 = ((unsigned)ux1 < (unsigned)WWI) ? 1.0f : 0.0f;        \
        const float vy0 = ((unsigned)uy0 < (unsigned)HH) ? 1.0f : 0.0f;         \
        const float vy1 = ((unsigned)uy1 < (unsigned)HH) ? 1.0f : 0.0f;         \
        cw[(s)][0] = (1.0f - fy) * (1.0f - fx) * vy0 * vx0;                     \
        cw[(s)][1] = (1.0f - fy) * fx          * vy0 * vx1;                     \
        cw[(s)][2] = fy          * (1.0f - fx) * vy1 * vx0;                     \
        cw[(s)][3] = fy          * fx          * vy1 * vx1;                     \
        const int cx0 = iclamp(ux0, 0, WWI - 1), cx1 = iclamp(ux1, 0, WWI - 1); \
        const int cy0 = iclamp(uy0, 0, HH - 1),  cy1 = iclamp(uy1, 0, HH - 1);  \
        const unsigned short* r00 = xtb + (size_t)(cy0 * WWI + cx0) * CC;       \
        const unsigned short* r01 = xtb + (size_t)(cy0 * WWI + cx1) * CC;       \
        const unsigned short* r10 = xtb + (size_t)(cy1 * WWI + cx0) * CC;       \
        const unsigned short* r11 = xtb + (size_t)(cy1 * WWI + cx1) * CC;       \
        cb[(s)][0] = *(const uint4v*)(r00 + c0);                                \
        cb[(s)][1] = *(const uint4v*)(r00 + c1);                                \
        cb[(s)][2] = *(const uint4v*)(r01 + c0);                                \
        cb[(s)][3] = *(const uint4v*)(r01 + c1);                                \
        cb[(s)][4] = *(const uint4v*)(r10 + c0);                                \
        cb[(s)][5] = *(const uint4v*)(r10 + c1);                                \
        cb[(s)][6] = *(const uint4v*)(r11 + c0);                                \
        cb[(s)][7] = *(const uint4v*)(r11 + c1);                                \
    } while (0)

    // PROCESS(k,s): pin the 8 vectors (forces wide loads, completed HERE),
    // then waf frag loads + interpolation + 8 MFMAs.
#define PROCESS(k, s) do {                                                      \
        asm volatile("" : "+v"(cb[(s)][0]), "+v"(cb[(s)][1]),                   \
                          "+v"(cb[(s)][2]), "+v"(cb[(s)][3]),                   \
                          "+v"(cb[(s)][4]), "+v"(cb[(s)][5]),                   \
                          "+v"(cb[(s)][6]), "+v"(cb[(s)][7]));                  \
        const float w00 = cw[(s)][0], w01 = cw[(s)][1];                         \
        const float w10 = cw[(s)][2], w11 = cw[(s)][3];                         \
        const unsigned short* wk = waf + (size_t)(k) * 8 * 512 + lane * 8;      \
        bf16x8 af[8];                                                           \
        _Pragma("unroll")                                                       \
        for (int q = 0; q < 8; ++q) af[q] = *(const bf16x8*)(wk + (size_t)q * 512); \
        bf16x8 bf0, bf1;                                                        \
        __hip_bfloat162* rp0 = (__hip_bfloat162*)&bf0;                          \
        __hip_bfloat162* rp1 = (__hip_bfloat162*)&bf1;                          \
        _Pragma("unroll")                                                       \
        for (int i = 0; i < 4; ++i) {                                           \
            float vlo = w00 * bfl(cb[(s)][0][i]) + w01 * bfl(cb[(s)][2][i])     \
                      + w10 * bfl(cb[(s)][4][i]) + w11 * bfl(cb[(s)][6][i]);    \
            float vhi = w00 * bfh(cb[(s)][0][i]) + w01 * bfh(cb[(s)][2][i])     \
                      + w10 * bfh(cb[(s)][4][i]) + w11 * bfh(cb[(s)][6][i]);    \
            rp0[i] = __hip_bfloat162{__float2bfloat16(vlo), __float2bfloat16(vhi)}; \
            float ulo = w00 * bfl(cb[(s)][1][i]) + w01 * bfl(cb[(s)][3][i])     \
                      + w10 * bfl(cb[(s)][5][i]) + w11 * bfl(cb[(s)][7][i]);    \
            float uhi = w00 * bfh(cb[(s)][1][i]) + w01 * bfh(cb[(s)][3][i])     \
                      + w10 * bfh(cb[(s)][5][i]) + w11 * bfh(cb[(s)][7][i]);    \
            rp1[i] = __hip_bfloat162{__float2bfloat16(ulo), __float2bfloat16(uhi)}; \
        }                                                                       \
        _Pragma("unroll")                                                       \
        for (int m = 0; m < 4; ++m)                                             \
            acc[m] = __builtin_amdgcn_mfma_f32_16x16x32_bf16(af[m], bf0, acc[m], 0, 0, 0); \
        _Pragma("unroll")                                                       \
        for (int m = 0; m < 4; ++m)                                             \
            acc[m] = __builtin_amdgcn_mfma_f32_16x16x32_bf16(af[4 + m], bf1, acc[m], 0, 0, 0); \
    } while (0)

    // Schedule: I0 I1 P0 I2 P1 I3 P2 ... I8 P7 P8
    // During PROCESS(k), tap k+1's loads are outstanding (pinned at P(k+1)).
    ISSUE(0, 0);
    ISSUE(1, 1);
    PROCESS(0, 0);
    ISSUE(2, 0);
    PROCESS(1, 1);
    ISSUE(3, 1);
    PROCESS(2, 0);
    ISSUE(4, 0);
    PROCESS(3, 1);
    ISSUE(5, 1);
    PROCESS(4, 0);
    ISSUE(6, 0);
    PROCESS(5, 1);
    ISSUE(7, 1);
    PROCESS(6, 0);
    ISSUE(8, 0);
    PROCESS(7, 1);
    PROCESS(8, 0);

#undef ISSUE
#undef PROCESS

    // epilogue: D layout col = lane&15 (px), row = hi*4 + j within each m-tile
    float* outb = out + (size_t)b * OO * HWSZ + p0 + px;
#pragma unroll
    for (int m = 0; m < 4; ++m) {
        const int ob = m * 16 + hi * 4;
        const float4 bs = *(const float4*)(bias + ob);
#pragma unroll
        for (int j = 0; j < 4; ++j) {
            outb[(size_t)(ob + j) * HWSZ] = acc[m][j] + ((const float*)&bs)[j];
        }
    }
}

// ---------- fallback (round-1 fp32 path, used only if ws too small) ----------
__global__ __launch_bounds__(256) void deform_conv_fallback(
        const float* __restrict__ x, const float* __restrict__ off,
        const float* __restrict__ wmat, const float* __restrict__ bias,
        float* __restrict__ out) {
    const int b = blockIdx.y;
    const int p = blockIdx.x * 256 + threadIdx.x;
    const int wo = p & (WWI - 1);
    const int ho = p >> 7;
    const float* xb = x + (size_t)b * CC * HWSZ;
    const float* offb = off + (size_t)b * 2 * KK * HWSZ + p;
    float acc[OO];
#pragma unroll
    for (int o = 0; o < OO; ++o) acc[o] = 0.0f;
#pragma unroll 1
    for (int k = 0; k < KK; ++k) {
        const float gx = offb[(size_t)(2 * k + 0) * HWSZ] + (float)wo;
        const float gy = offb[(size_t)(2 * k + 1) * HWSZ] + (float)ho;
        const float fxf = floorf(gx), fyf = floorf(gy);
        const float fx = gx - fxf, fy = gy - fyf;
        const int ux0 = (int)fxf - 1, ux1 = (int)fxf;
        const int uy0 = (int)fyf - 1, uy1 = (int)fyf;
        const float vx0 = ((unsigned)ux0 < (unsigned)WWI) ? 1.0f : 0.0f;
        const float vx1 = ((unsigned)ux1 < (unsigned)WWI) ? 1.0f : 0.0f;
        const float vy0 = ((unsigned)uy0 < (unsigned)HH) ? 1.0f : 0.0f;
        const float vy1 = ((unsigned)uy1 < (unsigned)HH) ? 1.0f : 0.0f;
        const float w00 = (1.0f - fy) * (1.0f - fx) * vy0 * vx0;
        const float w01 = (1.0f - fy) * fx * vy0 * vx1;
        const float w10 = fy * (1.0f - fx) * vy1 * vx0;
        const float w11 = fy * fx * vy1 * vx1;
        const int cx0 = iclamp(ux0, 0, WWI - 1), cx1 = iclamp(ux1, 0, WWI - 1);
        const int cy0 = iclamp(uy0, 0, HH - 1), cy1 = iclamp(uy1, 0, HH - 1);
        const int i00 = cy0 * WWI + cx0, i01 = cy0 * WWI + cx1;
        const int i10 = cy1 * WWI + cx0, i11 = cy1 * WWI + cx1;
#pragma unroll 4
        for (int c = 0; c < CC; ++c) {
            const float* xc = xb + (size_t)c * HWSZ;
            const float v = w00 * xc[i00] + w01 * xc[i01] + w10 * xc[i10] + w11 * xc[i11];
            const float* wrow = wmat + (size_t)(k * CC + c);
#pragma unroll
            for (int o = 0; o < OO; ++o) acc[o] = fmaf(wrow[(size_t)o * II], v, acc[o]);
        }
    }
    float* outb = out + (size_t)b * OO * HWSZ + p;
#pragma unroll
    for (int o = 0; o < OO; ++o) outb[(size_t)o * HWSZ] = acc[o] + bias[o];
}

extern "C" void kernel_launch(void* const* d_in, const int* in_sizes, int n_in,
                              void* d_out, int out_size, void* d_ws, size_t ws_size,
                              hipStream_t stream) {
    const float* x    = (const float*)d_in[0];
    const float* off  = (const float*)d_in[1];
    const float* w    = (const float*)d_in[2];
    const float* bias = (const float*)d_in[3];
    float* out = (float*)d_out;

    const size_t xt_bytes  = (size_t)BB * HWSZ * CC * sizeof(unsigned short); // 16.78 MB
    const size_t waf_bytes = (size_t)72 * 512 * sizeof(unsigned short);       // 73728 B

    if (ws_size >= xt_bytes + waf_bytes) {
        unsigned short* xt  = (unsigned short*)d_ws;
        unsigned short* wfp = (unsigned short*)((char*)d_ws + xt_bytes);
        prep_xt<<<dim3((HWSZ / 64) * BB), 256, 0, stream>>>(x, xt);
        prep_waf<<<(72 * 512 + 255) / 256, 256, 0, stream>>>(w, wfp);
        deform_mfma4<<<dim3((HWSZ / 64) * BB), 256, 0, stream>>>(xt, off, wfp, bias, out);
    } else {
        deform_conv_fallback<<<dim3(HWSZ / 256, BB), 256, 0, stream>>>(x, off, w, bias, out);
    }
}

// Round 7
// 54.882 us; speedup vs baseline: 1.7974x; 1.7944x over previous
//
#include <hip/hip_runtime.h>
#include <hip/hip_bf16.h>

// Problem constants
#define BB 8
#define CC 64
#define OO 64
#define HH 128
#define WWI 128
#define HWSZ (HH * WWI)     // 16384
#define KK 9                // 3x3 taps
#define II (KK * CC)        // 576

// patch / window geometry (main kernel)
#define PXW 16              // patch width  (x)
#define PYH 8               // patch height (y)
#define WNX 24              // window cols = PXW + 8
#define WNY 16              // window rows = PYH + 8
#define WROWS (WNX * WNY)   // 384 window (y,x) rows, each 64 ch * 2B = 128B

typedef __attribute__((ext_vector_type(8))) short bf16x8;
typedef __attribute__((ext_vector_type(4))) float f32x4;
typedef __attribute__((ext_vector_type(4))) unsigned int uint4v;

__device__ __forceinline__ int iclamp(int v, int lo, int hi) {
    return v < lo ? lo : (v > hi ? hi : v);
}
__device__ __forceinline__ unsigned short f2bf(float f) {  // RNE
    unsigned u = __float_as_uint(f);
    return (unsigned short)((u + 0x7fffu + ((u >> 16) & 1u)) >> 16);
}
__device__ __forceinline__ float bfl(unsigned u) { return __uint_as_float(u << 16); }
__device__ __forceinline__ float bfh(unsigned u) { return __uint_as_float(u & 0xffff0000u); }

// ---------- prep 1: x [B][C][H][W] f32 -> xt [B][H][W][C] bf16 (LDS transpose)
__global__ __launch_bounds__(256) void prep_xt(const float* __restrict__ x,
                                               unsigned short* __restrict__ xt) {
    __shared__ float tile[64][65];
    const int blk = blockIdx.x;
    const int b = blk & 7;
    const int p0 = (blk >> 3) * 64;
    const int t = threadIdx.x;
    const int a = t >> 6;   // 0..3
    const int q = t & 63;   // 0..63
    const float* xb = x + (size_t)b * CC * HWSZ + p0;
#pragma unroll
    for (int r = 0; r < 16; ++r) {
        int c = r * 4 + a;
        tile[c][q] = xb[(size_t)c * HWSZ + q];   // coalesced read
    }
    __syncthreads();
    unsigned short* xo = xt + ((size_t)b * HWSZ + p0) * CC;
#pragma unroll
    for (int r = 0; r < 16; ++r) {
        int pl = r * 4 + a;
        xo[(size_t)pl * CC + q] = f2bf(tile[q][pl]);  // coalesced 2B x 64 write
    }
}

// ---------- prep 2: W -> fragment-ordered bf16 layout
// waf[slab][lane][j], slab = (k*2+kc)*4 + m, value =
//   W.flat[o = m*16+(lane&15)][i = k*64 + kc*32 + (lane>>4)*8 + j]
__global__ void prep_waf(const float* __restrict__ w, unsigned short* __restrict__ waf) {
    int tid = blockIdx.x * 256 + threadIdx.x;
    if (tid < 72 * 512) {
        int slab = tid >> 9;           // 0..71
        int r = tid & 511;
        int l = r >> 3, j = r & 7;
        int m = slab & 3;
        int kc = (slab >> 2) & 1;
        int k = slab >> 3;
        int o = m * 16 + (l & 15);
        int i = k * 64 + kc * 32 + (l >> 4) * 8 + j;
        waf[tid] = f2bf(w[(size_t)o * II + i]);
    }
}

// ---------- main: per block one 16x8 output patch (128 px), window in LDS.
// 4 waves; wave w handles rows y0+2w, y0+2w+1 (2 MFMA n-tiles of 16 px).
// Corner samples come from the 48KB LDS window (XOR-swizzled chunks);
// rare out-of-window taps fall back to clamped global loads.
__global__ __launch_bounds__(256, 3) void deform_mfma5(
        const unsigned short* __restrict__ xt,   // [B][H][W][C] bf16
        const float* __restrict__ off,           // [B][2K][H][W]
        const unsigned short* __restrict__ waf,  // frag-ordered W, bf16
        const float* __restrict__ bias,          // [O]
        float* __restrict__ out) {               // [B][O][H][W]
    __shared__ unsigned short win[WROWS * CC];   // 384 rows * 128B = 48KB

    const int blk = blockIdx.x;
    const int b = blk & 7;                 // XCD-ownership: image b on XCD b
    const int pidx = blk >> 3;             // 0..127
    const int y0 = (pidx >> 3) * PYH;      // 16 y-patches
    const int x0 = (pidx & 7) * PXW;       // 8 x-patches
    const int xleft = x0 - 4, ytop = y0 - 4;

    const int t = threadIdx.x;
    const int wave = t >> 6;
    const int lane = t & 63;
    const int fm = lane & 15;              // px-in-tile (B col)
    const int hi = lane >> 4;              // 0..3 (k-chunk)
    const int c0s = hi * 8;                // short offset, kc=0 chunk
    const int c1s = 32 + hi * 8;           // short offset, kc=1 chunk

    const unsigned short* xtb = xt + (size_t)b * HWSZ * CC;
    // per-lane offset source: pixel (y0+2w [+nt], x0+fm)
    const float* offpx = off + (size_t)b * 2 * KK * HWSZ
                             + (size_t)(y0 + wave * 2) * WWI + x0 + fm;

    // ---- issue tap-0 offset loads before the (long) window staging ----
    float oxb[2][2], oyb[2][2];            // [buf][nt], all indices compile-time
#pragma unroll
    for (int nt = 0; nt < 2; ++nt) {
        oxb[0][nt] = offpx[(size_t)0 * HWSZ + nt * WWI];
        oyb[0][nt] = offpx[(size_t)1 * HWSZ + nt * WWI];
    }

    // ---- stage window: rows (cy,cx) in [ytop,ytop+15] x [xleft,xleft+23] ----
    {
        const int tch = t & 7;             // 16B chunk within a row
        const int rb = t >> 3;             // 0..31
#pragma unroll
        for (int sw = 0; sw < 12; ++sw) {
            const int r = sw * 32 + rb;    // window row 0..383
            const int wy = r / WNX, wx = r - wy * WNX;
            const int cy = ytop + wy, cx = xleft + wx;
            if (((unsigned)cy < (unsigned)HH) && ((unsigned)cx < (unsigned)WWI)) {
                const uint4v v = *(const uint4v*)(xtb + (size_t)(cy * WWI + cx) * CC + tch * 8);
                *(uint4v*)&win[r * CC + ((tch ^ (r & 7)) << 3)] = v;  // swizzled
            }
        }
    }
    __syncthreads();

    f32x4 acc[2][4];
#pragma unroll
    for (int nt = 0; nt < 2; ++nt)
#pragma unroll
        for (int m = 0; m < 4; ++m) acc[nt][m] = (f32x4)(0.0f);

#pragma unroll
    for (int k = 0; k < KK; ++k) {
        const int cur = k & 1, nxt = cur ^ 1;
        if (k + 1 < KK) {                  // depth-1 offset prefetch
#pragma unroll
            for (int nt = 0; nt < 2; ++nt) {
                oxb[nxt][nt] = offpx[(size_t)(2 * k + 2) * HWSZ + nt * WWI];
                oyb[nxt][nt] = offpx[(size_t)(2 * k + 3) * HWSZ + nt * WWI];
            }
        }
        // A-fragments for tap k (reused by both n-tiles)
        const unsigned short* wk = waf + (size_t)k * 8 * 512 + lane * 8;
        bf16x8 af[8];
#pragma unroll
        for (int q = 0; q < 8; ++q) af[q] = *(const bf16x8*)(wk + (size_t)q * 512);

#pragma unroll
        for (int nt = 0; nt < 2; ++nt) {
            const float gx = oxb[cur][nt] + (float)(x0 + fm);        // padded coords
            const float gy = oyb[cur][nt] + (float)(y0 + wave * 2 + nt);
            const float fxf = floorf(gx), fyf = floorf(gy);
            const float fx = gx - fxf, fy = gy - fyf;
            const int ux0 = (int)fxf - 1, ux1 = (int)fxf;            // unpadded
            const int uy0 = (int)fyf - 1, uy1 = (int)fyf;
            const float vx0 = ((unsigned)ux0 < (unsigned)WWI) ? 1.0f : 0.0f;
            const float vx1 = ((unsigned)ux1 < (unsigned)WWI) ? 1.0f : 0.0f;
            const float vy0 = ((unsigned)uy0 < (unsigned)HH) ? 1.0f : 0.0f;
            const float vy1 = ((unsigned)uy1 < (unsigned)HH) ? 1.0f : 0.0f;
            const float w00 = (1.0f - fy) * (1.0f - fx) * vy0 * vx0;
            const float w01 = (1.0f - fy) * fx          * vy0 * vx1;
            const float w10 = fy          * (1.0f - fx) * vy1 * vx0;
            const float w11 = fy          * fx          * vy1 * vx1;
            const int cx0 = iclamp(ux0, 0, WWI - 1), cx1 = iclamp(ux1, 0, WWI - 1);
            const int cy0 = iclamp(uy0, 0, HH - 1),  cy1 = iclamp(uy1, 0, HH - 1);

            const bool inw = (cx0 >= xleft) & (cx1 <= xleft + WNX - 1)
                           & (cy0 >= ytop) & (cy1 <= ytop + WNY - 1);
            // window coords (clamped so LDS addrs stay in-bounds even when !inw)
            const int wx0 = iclamp(cx0 - xleft, 0, WNX - 1);
            const int wx1 = iclamp(cx1 - xleft, 0, WNX - 1);
            const int wy0 = iclamp(cy0 - ytop, 0, WNY - 1);
            const int wy1 = iclamp(cy1 - ytop, 0, WNY - 1);
            const int r00 = wy0 * WNX + wx0, r01 = wy0 * WNX + wx1;
            const int r10 = wy1 * WNX + wx0, r11 = wy1 * WNX + wx1;

            // 8 LDS corner reads (swizzled chunk slots: slot = (hi + kc*4) ^ (row&7))
#define LDSRD(r, kc) (*(const uint4v*)&win[(r) * CC + ((((hi) + ((kc) << 2)) ^ ((r) & 7)) << 3)])
            uint4v A0 = LDSRD(r00, 0), A1 = LDSRD(r00, 1);
            uint4v B0 = LDSRD(r01, 0), B1 = LDSRD(r01, 1);
            uint4v C0 = LDSRD(r10, 0), C1 = LDSRD(r10, 1);
            uint4v D0 = LDSRD(r11, 0), D1 = LDSRD(r11, 1);
#undef LDSRD
            if (!inw) {                    // rare (~0.2% of lanes): global fallback
                const unsigned short* g00 = xtb + (size_t)(cy0 * WWI + cx0) * CC;
                const unsigned short* g01 = xtb + (size_t)(cy0 * WWI + cx1) * CC;
                const unsigned short* g10 = xtb + (size_t)(cy1 * WWI + cx0) * CC;
                const unsigned short* g11 = xtb + (size_t)(cy1 * WWI + cx1) * CC;
                A0 = *(const uint4v*)(g00 + c0s);  A1 = *(const uint4v*)(g00 + c1s);
                B0 = *(const uint4v*)(g01 + c0s);  B1 = *(const uint4v*)(g01 + c1s);
                C0 = *(const uint4v*)(g10 + c0s);  C1 = *(const uint4v*)(g10 + c1s);
                D0 = *(const uint4v*)(g11 + c0s);  D1 = *(const uint4v*)(g11 + c1s);
            }

            // interpolate -> this lane's B-fragments
            bf16x8 bf0, bf1;
            __hip_bfloat162* rp0 = (__hip_bfloat162*)&bf0;
            __hip_bfloat162* rp1 = (__hip_bfloat162*)&bf1;
#pragma unroll
            for (int i = 0; i < 4; ++i) {
                float vlo = w00 * bfl(A0[i]) + w01 * bfl(B0[i])
                          + w10 * bfl(C0[i]) + w11 * bfl(D0[i]);
                float vhi = w00 * bfh(A0[i]) + w01 * bfh(B0[i])
                          + w10 * bfh(C0[i]) + w11 * bfh(D0[i]);
                rp0[i] = __hip_bfloat162{__float2bfloat16(vlo), __float2bfloat16(vhi)};
                float ulo = w00 * bfl(A1[i]) + w01 * bfl(B1[i])
                          + w10 * bfl(C1[i]) + w11 * bfl(D1[i]);
                float uhi = w00 * bfh(A1[i]) + w01 * bfh(B1[i])
                          + w10 * bfh(C1[i]) + w11 * bfh(D1[i]);
                rp1[i] = __hip_bfloat162{__float2bfloat16(ulo), __float2bfloat16(uhi)};
            }
#pragma unroll
            for (int m = 0; m < 4; ++m)
                acc[nt][m] = __builtin_amdgcn_mfma_f32_16x16x32_bf16(af[m], bf0, acc[nt][m], 0, 0, 0);
#pragma unroll
            for (int m = 0; m < 4; ++m)
                acc[nt][m] = __builtin_amdgcn_mfma_f32_16x16x32_bf16(af[4 + m], bf1, acc[nt][m], 0, 0, 0);
        }
    }

    // epilogue: D col = fm (px), D row = hi*4 + j within m-tile -> o = m*16+hi*4+j
#pragma unroll
    for (int nt = 0; nt < 2; ++nt) {
        float* outb = out + (size_t)b * OO * HWSZ
                          + (size_t)(y0 + wave * 2 + nt) * WWI + x0 + fm;
#pragma unroll
        for (int m = 0; m < 4; ++m) {
            const int ob = m * 16 + hi * 4;
            const float4 bs = *(const float4*)(bias + ob);
#pragma unroll
            for (int j = 0; j < 4; ++j) {
                outb[(size_t)(ob + j) * HWSZ] = acc[nt][m][j] + ((const float*)&bs)[j];
            }
        }
    }
}

// ---------- fallback (round-1 fp32 path, used only if ws too small) ----------
__global__ __launch_bounds__(256) void deform_conv_fallback(
        const float* __restrict__ x, const float* __restrict__ off,
        const float* __restrict__ wmat, const float* __restrict__ bias,
        float* __restrict__ out) {
    const int b = blockIdx.y;
    const int p = blockIdx.x * 256 + threadIdx.x;
    const int wo = p & (WWI - 1);
    const int ho = p >> 7;
    const float* xb = x + (size_t)b * CC * HWSZ;
    const float* offb = off + (size_t)b * 2 * KK * HWSZ + p;
    float acc[OO];
#pragma unroll
    for (int o = 0; o < OO; ++o) acc[o] = 0.0f;
#pragma unroll 1
    for (int k = 0; k < KK; ++k) {
        const float gx = offb[(size_t)(2 * k + 0) * HWSZ] + (float)wo;
        const float gy = offb[(size_t)(2 * k + 1) * HWSZ] + (float)ho;
        const float fxf = floorf(gx), fyf = floorf(gy);
        const float fx = gx - fxf, fy = gy - fyf;
        const int ux0 = (int)fxf - 1, ux1 = (int)fxf;
        const int uy0 = (int)fyf - 1, uy1 = (int)fyf;
        const float vx0 = ((unsigned)ux0 < (unsigned)WWI) ? 1.0f : 0.0f;
        const float vx1 = ((unsigned)ux1 < (unsigned)WWI) ? 1.0f : 0.0f;
        const float vy0 = ((unsigned)uy0 < (unsigned)HH) ? 1.0f : 0.0f;
        const float vy1 = ((unsigned)uy1 < (unsigned)HH) ? 1.0f : 0.0f;
        const float w00 = (1.0f - fy) * (1.0f - fx) * vy0 * vx0;
        const float w01 = (1.0f - fy) * fx * vy0 * vx1;
        const float w10 = fy * (1.0f - fx) * vy1 * vx0;
        const float w11 = fy * fx * vy1 * vx1;
        const int cx0 = iclamp(ux0, 0, WWI - 1), cx1 = iclamp(ux1, 0, WWI - 1);
        const int cy0 = iclamp(uy0, 0, HH - 1), cy1 = iclamp(uy1, 0, HH - 1);
        const int i00 = cy0 * WWI + cx0, i01 = cy0 * WWI + cx1;
        const int i10 = cy1 * WWI + cx0, i11 = cy1 * WWI + cx1;
#pragma unroll 4
        for (int c = 0; c < CC; ++c) {
            const float* xc = xb + (size_t)c * HWSZ;
            const float v = w00 * xc[i00] + w01 * xc[i01] + w10 * xc[i10] + w11 * xc[i11];
            const float* wrow = wmat + (size_t)(k * CC + c);
#pragma unroll
            for (int o = 0; o < OO; ++o) acc[o] = fmaf(wrow[(size_t)o * II], v, acc[o]);
        }
    }
    float* outb = out + (size_t)b * OO * HWSZ + p;
#pragma unroll
    for (int o = 0; o < OO; ++o) outb[(size_t)o * HWSZ] = acc[o] + bias[o];
}

extern "C" void kernel_launch(void* const* d_in, const int* in_sizes, int n_in,
                              void* d_out, int out_size, void* d_ws, size_t ws_size,
                              hipStream_t stream) {
    const float* x    = (const float*)d_in[0];
    const float* off  = (const float*)d_in[1];
    const float* w    = (const float*)d_in[2];
    const float* bias = (const float*)d_in[3];
    float* out = (float*)d_out;

    const size_t xt_bytes  = (size_t)BB * HWSZ * CC * sizeof(unsigned short); // 16.78 MB
    const size_t waf_bytes = (size_t)72 * 512 * sizeof(unsigned short);       // 73728 B

    if (ws_size >= xt_bytes + waf_bytes) {
        unsigned short* xt  = (unsigned short*)d_ws;
        unsigned short* wfp = (unsigned short*)((char*)d_ws + xt_bytes);
        prep_xt<<<dim3((HWSZ / 64) * BB), 256, 0, stream>>>(x, xt);
        prep_waf<<<(72 * 512 + 255) / 256, 256, 0, stream>>>(w, wfp);
        // 8 images x (16 y-patches * 8 x-patches) = 1024 blocks
        deform_mfma5<<<dim3(BB * (HH / PYH) * (WWI / PXW)), 256, 0, stream>>>(
            xt, off, wfp, bias, out);
    } else {
        deform_conv_fallback<<<dim3(HWSZ / 256, BB), 256, 0, stream>>>(x, off, w, bias, out);
    }
}